// Round 12
// baseline (647.641 us; speedup 1.0000x reference)
//
#include <hip/hip_runtime.h>
#include <hip/hip_cooperative_groups.h>

static inline int ceil_div(long long a, long long b) { return (int)((a + b - 1) / b); }

typedef __attribute__((ext_vector_type(8))) short bf16x8;
typedef __attribute__((ext_vector_type(4))) float f32x4;

#define TILE 8192          // edges per bucket tile
#define BKSH 9             // bucket = dst >> 9  (512 dsts per bucket)

__device__ __forceinline__ float lrelu(float t) { return t > 0.f ? t : 0.2f * t; }

__device__ __forceinline__ void atomAddF(float* p, float v) {
  unsafeAtomicAdd(p, v);  // hardware global_atomic_add_f32
}

// float -> bf16 with round-to-nearest-even
__device__ __forceinline__ unsigned int f2bf(float f) {
  unsigned int u = __float_as_uint(f);
  unsigned int r = ((u >> 16) & 1u) + 0x7fffu;
  return (u + r) >> 16;
}

// ---------------- prep: input convert + all weight transposes, one launch ----------
__global__ void prep_all(const float* __restrict__ X, unsigned short* __restrict__ Xb, int n4,
                         const float* __restrict__ W1, const float* __restrict__ W2,
                         const float* __restrict__ W3, unsigned short* __restrict__ Wt1,
                         unsigned short* __restrict__ Wt2, unsigned short* __restrict__ Wt3) {
  int i = blockIdx.x * blockDim.x + threadIdx.x;
  if (i < n4) {
    const float4 v = ((const float4*)X)[i];
    uint2 o;
    o.x = f2bf(v.x) | (f2bf(v.y) << 16);
    o.y = f2bf(v.z) | (f2bf(v.w) << 16);
    ((uint2*)Xb)[i] = o;
    return;
  }
  int idx = i - n4;
  const float* W; unsigned short* Wt; int DOUTv;
  if (idx < 16384)      { W = W1; Wt = Wt1;               DOUTv = 128; }
  else if (idx < 32768) { W = W2; Wt = Wt2; idx -= 16384; DOUTv = 128; }
  else if (idx < 40960) { W = W3; Wt = Wt3; idx -= 32768; DOUTv = 64;  }
  else return;
  const int k = idx / DOUTv, n = idx % DOUTv;
  Wt[n * 128 + k] = (unsigned short)f2bf(W[idx]);
}

// ---------------- MFMA GEMM + attention scores (CG=2 via LDS score combine) --------
template<int DOUT>
__launch_bounds__(256)
__global__ void gemm_mfma(const unsigned short* __restrict__ Xb, const unsigned short* __restrict__ Wt,
                          const float* __restrict__ avs, const float* __restrict__ avd,
                          unsigned short* __restrict__ Hb, float* __restrict__ Ss,
                          float* __restrict__ Sd, int N, int RG) {
  constexpr int DIN = 128;
  constexpr int CG = DOUT / 64;     // 2 (DOUT=128) or 1 (DOUT=64)
  constexpr int RPB = 4 / CG;       // row-groups per block
  __shared__ float sps[RPB][2][64], spd[RPB][2][64];

  const int wv = threadIdx.x >> 6;
  const int rgl = wv / CG;
  const int cg  = wv % CG;
  const int rg = blockIdx.x * RPB + rgl;
  const bool active = rg < RG;
  const int lane = threadIdx.x & 63;
  const int l16 = lane & 15, quad = lane >> 4;
  const int row0 = rg * 64, colw0 = cg * 64;

  if (active) {
    int xoff[4], woff[4];
#pragma unroll
    for (int t = 0; t < 4; t++) {
      int m = row0 + t * 16 + l16; if (m > N - 1) m = N - 1;
      xoff[t] = m * DIN + quad * 8;
      woff[t] = (colw0 + t * 16 + l16) * DIN + quad * 8;
    }

    f32x4 acc[4][4];
#pragma unroll
    for (int a = 0; a < 4; a++)
#pragma unroll
      for (int c = 0; c < 4; c++) acc[a][c] = (f32x4)0.f;

#pragma unroll
    for (int kk = 0; kk < 4; kk++) {
      bf16x8 aw[4], bx[4];
#pragma unroll
      for (int t = 0; t < 4; t++) aw[t] = *(const bf16x8*)(Wt + woff[t] + kk * 32);
#pragma unroll
      for (int t = 0; t < 4; t++) bx[t] = *(const bf16x8*)(Xb + xoff[t] + kk * 32);
#pragma unroll
      for (int wt = 0; wt < 4; wt++)
#pragma unroll
        for (int xt = 0; xt < 4; xt++)
          acc[wt][xt] = __builtin_amdgcn_mfma_f32_16x16x32_bf16(aw[wt], bx[xt], acc[wt][xt], 0, 0, 0);
    }

    float4 af[4], df[4];
#pragma unroll
    for (int wt = 0; wt < 4; wt++) {
      af[wt] = *(const float4*)(avs + colw0 + wt * 16 + quad * 4);
      df[wt] = *(const float4*)(avd + colw0 + wt * 16 + quad * 4);
    }
#pragma unroll
    for (int xt = 0; xt < 4; xt++) {
      const int m = row0 + xt * 16 + l16;
      float ps = 0.f, pd = 0.f;
#pragma unroll
      for (int wt = 0; wt < 4; wt++) {
        const f32x4 c = acc[wt][xt];
        ps += c[0]*af[wt].x + c[1]*af[wt].y + c[2]*af[wt].z + c[3]*af[wt].w;
        pd += c[0]*df[wt].x + c[1]*df[wt].y + c[2]*df[wt].z + c[3]*df[wt].w;
      }
      ps += __shfl_xor(ps, 16); ps += __shfl_xor(ps, 32);
      pd += __shfl_xor(pd, 16); pd += __shfl_xor(pd, 32);
      if (quad == 0) {
        if (CG == 2) {
          sps[rgl][cg][xt * 16 + l16] = ps;
          spd[rgl][cg][xt * 16 + l16] = pd;
        } else if (m < N) {
          Ss[m] = ps; Sd[m] = pd;
        }
      }
      if (m < N) {
        unsigned short* hp = Hb + (size_t)m * DOUT + colw0 + quad * 4;
#pragma unroll
        for (int wt = 0; wt < 4; wt++) {
          const f32x4 c = acc[wt][xt];
          uint2 o;
          o.x = f2bf(c[0]) | (f2bf(c[1]) << 16);
          o.y = f2bf(c[2]) | (f2bf(c[3]) << 16);
          *(uint2*)(hp + wt * 16) = o;
        }
      }
    }
  }
  if (CG == 2) {
    __syncthreads();
    if (active && cg == 0) {
      const int m = row0 + lane;
      if (m < N) {
        Ss[m] = sps[rgl][0][lane] + sps[rgl][1][lane];
        Sd[m] = spd[rgl][0][lane] + spd[rgl][1][lane];
      }
    }
  }
}

// ---------------- CSR build: ONE cooperative kernel (5 phases, grid.sync between) ----
__launch_bounds__(256)
__global__ void coop_csr(const int* __restrict__ src, const int* __restrict__ dstv,
                         int* __restrict__ bh, int* __restrict__ tot,
                         int* __restrict__ bucketBase, int* __restrict__ rowptr,
                         unsigned int* __restrict__ pairs, int* __restrict__ srcs,
                         int E, int N, int NBA, int NBUK) {
  namespace cg = cooperative_groups;
  cg::grid_group grid = cg::this_grid();
  __shared__ int A[512], Bf[512], Cf[256];
  const int t = threadIdx.x;

  // phase 1: per-tile bucket histogram
  for (int blk = blockIdx.x; blk < NBA; blk += gridDim.x) {
    A[t] = 0; __syncthreads();
    const int base = blk * TILE, end = min(E, base + TILE);
    for (int i = base + t; i < end; i += 256) atomicAdd(&A[dstv[i] >> BKSH], 1);
    __syncthreads();
    if (t < NBUK) bh[blk * NBUK + t] = A[t];
    __syncthreads();
  }
  grid.sync();

  // phase 2: per-bucket column scan -> exclusive per-tile prefixes + totals
  for (int b = blockIdx.x; b < NBUK; b += gridDim.x) {
    int carry = 0;
    for (int c0 = 0; c0 < NBA; c0 += 256) {
      const int idx = c0 + t;
      const int v = (idx < NBA) ? bh[idx * NBUK + b] : 0;
      A[t] = v; __syncthreads();
      for (int off = 1; off < 256; off <<= 1) {
        int u = (t >= off) ? A[t - off] : 0; __syncthreads();
        A[t] += u; __syncthreads();
      }
      if (idx < NBA) bh[idx * NBUK + b] = carry + A[t] - v;
      carry += A[255]; __syncthreads();
    }
    if (t == 0) tot[b] = carry;
    __syncthreads();
  }
  grid.sync();

  // phase 3: bucket-base scan (block 0)
  if (blockIdx.x == 0) {
    int carry = 0;
    for (int c0 = 0; c0 < NBUK; c0 += 256) {
      const int idx = c0 + t;
      const int v = (idx < NBUK) ? tot[idx] : 0;
      A[t] = v; __syncthreads();
      for (int off = 1; off < 256; off <<= 1) {
        int u = (t >= off) ? A[t - off] : 0; __syncthreads();
        A[t] += u; __syncthreads();
      }
      if (idx < NBUK) bucketBase[idx] = carry + A[t] - v;
      carry += A[255]; __syncthreads();
    }
    if (t == 0) { bucketBase[NBUK] = E; rowptr[N] = E; }
  }
  grid.sync();

  // phase 4: scatter packed (src<<BKSH | localDst) into bucket regions
  for (int blk = blockIdx.x; blk < NBA; blk += gridDim.x) {
    if (t < NBUK) A[t] = bh[blk * NBUK + t] + bucketBase[t];
    __syncthreads();
    const int base = blk * TILE, end = min(E, base + TILE);
    for (int i = base + t; i < end; i += 256) {
      const int d = dstv[i];
      const int pos = atomicAdd(&A[d >> BKSH], 1);
      pairs[pos] = ((unsigned int)src[i] << BKSH) | (unsigned int)(d & ((1 << BKSH) - 1));
    }
    __syncthreads();
  }
  grid.sync();

  // phase 5: per-bucket 512-counter hist/scan -> rowptr + ranked srcs
  for (int r = blockIdx.x; r < NBUK; r += gridDim.x) {
    const int p0 = bucketBase[r], p1 = bucketBase[r + 1];
    A[t] = 0; A[t + 256] = 0; __syncthreads();
    for (int i = p0 + t; i < p1; i += 256) atomicAdd(&A[pairs[i] & 511u], 1);
    __syncthreads();
    const int c0 = A[2 * t], c1 = A[2 * t + 1];
    const int pr = c0 + c1;
    Cf[t] = pr; __syncthreads();
    for (int off = 1; off < 256; off <<= 1) {
      int v = (t >= off) ? Cf[t - off] : 0; __syncthreads();
      Cf[t] += v; __syncthreads();
    }
    const int pbase = Cf[t] - pr;
    Bf[2 * t] = pbase; Bf[2 * t + 1] = pbase + c0;
    __syncthreads();
    const int d0 = (r << BKSH) + t;
    if (d0 < N) rowptr[d0] = p0 + Bf[t];
    const int d1 = d0 + 256;
    if (d1 < N) rowptr[d1] = p0 + Bf[t + 256];
    __syncthreads();
    for (int i = p0 + t; i < p1; i += 256) {
      const unsigned int w = pairs[i];
      const int pos = atomicAdd(&Bf[w & 511u], 1);
      srcs[p0 + pos] = (int)(w >> BKSH);
    }
    __syncthreads();
  }
}

// ---------------- fused per-dst gather: single-pass, no segment-max ----------------
// MEAN=true (layer 3): block-reduce 16 nodes' outputs into 64-col LDS sum, 64 scaled
// global atomics per block; no per-node output store.
template<int DOUT, bool OBF, bool MEAN>
__launch_bounds__(256)
__global__ void node_gather(const int* __restrict__ rowptr, const int* __restrict__ srcs,
                            const float* __restrict__ Ss, const float* __restrict__ Sd,
                            const unsigned short* __restrict__ Hb, const float* __restrict__ b,
                            unsigned short* __restrict__ outb, float* __restrict__ outMean,
                            float scale, int N) {
  constexpr int EPL = DOUT / 16;          // bf16 elems per lane (8 or 4)
  __shared__ uint2 swL[16][18];           // 16 slots + pad
  __shared__ float colsum[64];

  const int l16 = threadIdx.x & 15;
  const int grp = threadIdx.x >> 4;
  const int node = blockIdx.x * 16 + grp;
  if (MEAN) {
    if (threadIdx.x < 64) colsum[threadIdx.x] = 0.f;
    __syncthreads();
  }
  const bool act = node < N;
  const size_t colb = (size_t)l16 * EPL;
  float o[EPL];
#pragma unroll
  for (int k = 0; k < EPL; k++) o[k] = 0.f;

  if (act) {
    const int r0 = rowptr[node], r1 = rowptr[node + 1];
    const int deg = r1 - r0;
    const float sd = Sd[node];
    const float wself = __expf(lrelu(Ss[node] + sd));

    float acc[EPL];
#pragma unroll
    for (int k = 0; k < EPL; k++) acc[k] = 0.f;
    float lsum = 0.f;

    for (int j0 = 0; j0 < deg; j0 += 16) {
      const int idx = j0 + l16;
      int s = node; float w = 0.f;
      if (idx < deg) {
        s = srcs[r0 + idx];
        w = __expf(lrelu(Ss[s] + sd));
      }
      lsum += w;
      swL[grp][l16] = make_uint2((unsigned)s, __float_as_uint(w));
      const int cnt = min(16, deg - j0);
      int t = 0;
      for (; t + 4 <= cnt; t += 4) {
        const uint2 sw0 = swL[grp][t],     sw1 = swL[grp][t + 1];
        const uint2 sw2 = swL[grp][t + 2], sw3 = swL[grp][t + 3];
        const float w0 = __uint_as_float(sw0.y), w1 = __uint_as_float(sw1.y);
        const float w2 = __uint_as_float(sw2.y), w3 = __uint_as_float(sw3.y);
        if (EPL == 8) {
          const uint4 u0 = *(const uint4*)(Hb + (size_t)sw0.x * DOUT + colb);
          const uint4 u1 = *(const uint4*)(Hb + (size_t)sw1.x * DOUT + colb);
          const uint4 u2 = *(const uint4*)(Hb + (size_t)sw2.x * DOUT + colb);
          const uint4 u3 = *(const uint4*)(Hb + (size_t)sw3.x * DOUT + colb);
          const unsigned int a0[4] = {u0.x,u0.y,u0.z,u0.w}, a1[4] = {u1.x,u1.y,u1.z,u1.w};
          const unsigned int a2[4] = {u2.x,u2.y,u2.z,u2.w}, a3[4] = {u3.x,u3.y,u3.z,u3.w};
#pragma unroll
          for (int k = 0; k < 4; k++) {
            acc[2*k]   += __uint_as_float(a0[k] << 16) * w0 + __uint_as_float(a1[k] << 16) * w1
                        + __uint_as_float(a2[k] << 16) * w2 + __uint_as_float(a3[k] << 16) * w3;
            acc[2*k+1] += __uint_as_float(a0[k] & 0xffff0000u) * w0 + __uint_as_float(a1[k] & 0xffff0000u) * w1
                        + __uint_as_float(a2[k] & 0xffff0000u) * w2 + __uint_as_float(a3[k] & 0xffff0000u) * w3;
          }
        } else {
          const uint2 u0 = *(const uint2*)(Hb + (size_t)sw0.x * DOUT + colb);
          const uint2 u1 = *(const uint2*)(Hb + (size_t)sw1.x * DOUT + colb);
          const uint2 u2 = *(const uint2*)(Hb + (size_t)sw2.x * DOUT + colb);
          const uint2 u3 = *(const uint2*)(Hb + (size_t)sw3.x * DOUT + colb);
          const unsigned int a0[2] = {u0.x,u0.y}, a1[2] = {u1.x,u1.y};
          const unsigned int a2[2] = {u2.x,u2.y}, a3[2] = {u3.x,u3.y};
#pragma unroll
          for (int k = 0; k < 2; k++) {
            acc[2*k]   += __uint_as_float(a0[k] << 16) * w0 + __uint_as_float(a1[k] << 16) * w1
                        + __uint_as_float(a2[k] << 16) * w2 + __uint_as_float(a3[k] << 16) * w3;
            acc[2*k+1] += __uint_as_float(a0[k] & 0xffff0000u) * w0 + __uint_as_float(a1[k] & 0xffff0000u) * w1
                        + __uint_as_float(a2[k] & 0xffff0000u) * w2 + __uint_as_float(a3[k] & 0xffff0000u) * w3;
          }
        }
      }
      for (; t < cnt; t++) {
        const uint2 sw = swL[grp][t];
        const float w0 = __uint_as_float(sw.y);
        const unsigned short* pp = Hb + (size_t)sw.x * DOUT + colb;
#pragma unroll
        for (int k = 0; k < EPL / 2; k++) {
          const unsigned int u = ((const unsigned int*)pp)[k];
          acc[2*k]   += __uint_as_float(u << 16) * w0;
          acc[2*k+1] += __uint_as_float(u & 0xffff0000u) * w0;
        }
      }
    }

#pragma unroll
    for (int off = 8; off; off >>= 1) lsum += __shfl_xor(lsum, off);

    {
      const unsigned short* pp = Hb + (size_t)node * DOUT + colb;
#pragma unroll
      for (int k = 0; k < EPL / 2; k++) {
        const unsigned int u = ((const unsigned int*)pp)[k];
        acc[2*k]   += __uint_as_float(u << 16) * wself;
        acc[2*k+1] += __uint_as_float(u & 0xffff0000u) * wself;
      }
    }
    const float inv = 1.f / (lsum + wself);
#pragma unroll
    for (int k = 0; k < EPL; k++) o[k] = acc[k] * inv + b[colb + k];

    if (OBF) {
      if (EPL == 8) {
        uint4 u;
        u.x = f2bf(o[0]) | (f2bf(o[1]) << 16);
        u.y = f2bf(o[2]) | (f2bf(o[3]) << 16);
        u.z = f2bf(o[4]) | (f2bf(o[5]) << 16);
        u.w = f2bf(o[6]) | (f2bf(o[7]) << 16);
        *(uint4*)(outb + (size_t)node * DOUT + colb) = u;
      } else {
        uint2 u;
        u.x = f2bf(o[0]) | (f2bf(o[1]) << 16);
        u.y = f2bf(o[2]) | (f2bf(o[3]) << 16);
        *(uint2*)(outb + (size_t)node * DOUT + colb) = u;
      }
    }
  }

  if (MEAN) {
    if (act) {
#pragma unroll
      for (int k = 0; k < EPL; k++) atomicAdd(&colsum[colb + k], o[k]);
    }
    __syncthreads();
    if (threadIdx.x < 64) atomAddF(&outMean[threadIdx.x], colsum[threadIdx.x] * scale);
  }
}

extern "C" void kernel_launch(void* const* d_in, const int* in_sizes, int n_in,
                              void* d_out, int out_size, void* d_ws, size_t ws_size,
                              hipStream_t stream) {
  const float* x   = (const float*)d_in[0];
  const int*   ei  = (const int*)d_in[1];
  const float* W1  = (const float*)d_in[2];
  const float* as1 = (const float*)d_in[3];
  const float* ad1 = (const float*)d_in[4];
  const float* b1  = (const float*)d_in[5];
  const float* W2  = (const float*)d_in[6];
  const float* as2 = (const float*)d_in[7];
  const float* ad2 = (const float*)d_in[8];
  const float* b2  = (const float*)d_in[9];
  const float* W3  = (const float*)d_in[10];
  const float* as3 = (const float*)d_in[11];
  const float* ad3 = (const float*)d_in[12];
  const float* b3  = (const float*)d_in[13];

  const int N = in_sizes[0] / 128;
  const int E = in_sizes[1] / 2;
  const int* src  = ei;
  const int* dstv = ei + E;
  const int RG = ceil_div(N, 64);
  const int NBA = ceil_div(E, TILE);
  const int NBUK = ceil_div(N, 1 << BKSH);

  float* p = (float*)d_ws;
  float* SsSd = p; p += (size_t)2 * N;
  float* Ss = SsSd; float* Sd = SsSd + N;
  unsigned short* Xb = (unsigned short*)p; p += (size_t)N * 64;
  unsigned short* Hb = (unsigned short*)p; p += (size_t)N * 64;
  unsigned short* Wt1 = (unsigned short*)p; p += 128 * 128 / 2;
  unsigned short* Wt2 = (unsigned short*)p; p += 128 * 128 / 2;
  unsigned short* Wt3 = (unsigned short*)p; p += 128 * 64 / 2;
  int* ip = (int*)p;
  int* rowptr     = ip; ip += N + 1;
  int* bh         = ip; ip += (size_t)NBA * NBUK;
  int* tot        = ip; ip += NBUK;
  int* bucketBase = ip; ip += NBUK + 1;
  unsigned int* pairs = (unsigned int*)ip; ip += E;
  int* srcs       = ip; ip += E;

  // zero the output accumulator (layer-3 gather atomics into it)
  hipMemsetAsync(d_out, 0, 64 * sizeof(float), stream);

  // ---- CSR build: one cooperative kernel ----
  {
    int G = (NBA > NBUK) ? NBA : NBUK;
    if (G > 256) G = 256;
    void* args[] = {(void*)&src, (void*)&dstv, (void*)&bh, (void*)&tot,
                    (void*)&bucketBase, (void*)&rowptr, (void*)&pairs, (void*)&srcs,
                    (void*)&E, (void*)&N, (void*)&NBA, (void*)&NBUK};
    hipLaunchCooperativeKernel((const void*)coop_csr, dim3(G), dim3(256), args, 0, stream);
  }

  // ---- prep: input convert + weight transposes, one launch ----
  const int n4 = N * 32;
  prep_all<<<ceil_div((long long)n4 + 40960, 256), 256, 0, stream>>>(
      x, Xb, n4, W1, W2, W3, Wt1, Wt2, Wt3);

  const int GG = ceil_div(N, 16);
  const float scl = 1.0f / (float)N;
  // ---- layer 1 ----
  gemm_mfma<128><<<ceil_div(RG, 2), 256, 0, stream>>>(Xb, Wt1, as1, ad1, Hb, Ss, Sd, N, RG);
  node_gather<128, true, false><<<GG, 256, 0, stream>>>(rowptr, srcs, Ss, Sd, Hb, b1, Xb, nullptr, 0.f, N);
  // ---- layer 2 ----
  gemm_mfma<128><<<ceil_div(RG, 2), 256, 0, stream>>>(Xb, Wt2, as2, ad2, Hb, Ss, Sd, N, RG);
  node_gather<128, true, false><<<GG, 256, 0, stream>>>(rowptr, srcs, Ss, Sd, Hb, b2, Xb, nullptr, 0.f, N);
  // ---- layer 3 (gather fuses the column mean into d_out) ----
  gemm_mfma<64><<<ceil_div(RG, 4), 256, 0, stream>>>(Xb, Wt3, as3, ad3, Hb, Ss, Sd, N, RG);
  node_gather<64, false, true><<<GG, 256, 0, stream>>>(rowptr, srcs, Ss, Sd, Hb, b3, nullptr, (float*)d_out, scl, N);
}